// Round 6
// baseline (419.393 us; speedup 1.0000x reference)
//
#include <hip/hip_runtime.h>

typedef float f32x4 __attribute__((ext_vector_type(4)));
typedef float fvec4 __attribute__((ext_vector_type(4)));
typedef __bf16 bf16x8 __attribute__((ext_vector_type(8)));
typedef unsigned short u16;
typedef u16 u16x8 __attribute__((ext_vector_type(8)));
typedef u16 u16x4 __attribute__((ext_vector_type(4)));
typedef int i32x2 __attribute__((ext_vector_type(2)));

#define SCALE_Q 0.18257418583505536f  /* 30^-0.5 */

__device__ __forceinline__ u16 f2bf(float f) {
    union { __bf16 h; u16 u; } cv; cv.h = (__bf16)f; return cv.u;
}
__device__ __forceinline__ float bf2f(u16 u) {
    union { __bf16 h; u16 u; } cv; cv.u = u; return (float)cv.h;
}

// async global->LDS, 16B per lane; LDS dest = wave-uniform base + lane*16
#define GLD16(gsrc, ldst) __builtin_amdgcn_global_load_lds( \
    (const __attribute__((address_space(1))) unsigned*)(gsrc), \
    (__attribute__((address_space(3))) unsigned*)(ldst), 16, 0, 0)

// lane^16 cross-exchange pair: u[l]=(l&16)?b[l^16]:a[l]; v[l]=(l&16)?b[l]:a[l^16]
__device__ __forceinline__ void xswap16(int a, int b, int& u, int& v) {
#if __has_builtin(__builtin_amdgcn_permlane16_swap)
    i32x2 r = __builtin_amdgcn_permlane16_swap(a, b, false, false);
    u = r[0]; v = r[1];
#else
    int sa = __builtin_amdgcn_ds_swizzle(a, 0x401F);
    int sb = __builtin_amdgcn_ds_swizzle(b, 0x401F);
    bool hi = (threadIdx.x & 16) != 0;
    u = hi ? sb : a;
    v = hi ? b : sa;
#endif
}

// ---------------------------------------------------------------------------
// prep: weight transposes (bf16 [col][k] padded), bf16 bias table, K_pad fills
// ---------------------------------------------------------------------------
__device__ __forceinline__ void border_yx(int i, int& y, int& x) {
    // 4160 border (y,x) of a 264x264 grid with 4-wide frame
    if (i < 1056)      { y = i / 264; x = i % 264; }
    else if (i < 2112) { int j = i - 1056; y = 260 + j / 264; x = j % 264; }
    else               { int j = i - 2112; y = 4 + (j >> 3); int xx = j & 7;
                         x = (xx < 4) ? xx : 256 + xx; }
}

__global__ __launch_bounds__(256)
void prep_k(const float* __restrict__ qkv_w, const float* __restrict__ proj_w,
            const float* __restrict__ fc1_w, const float* __restrict__ fc2_w,
            const int* __restrict__ rpi, const float* __restrict__ rpb,
            u16* __restrict__ qkvT, u16* __restrict__ projT,
            u16* __restrict__ fc1T, u16* __restrict__ fc2T,
            u16* __restrict__ bias5, unsigned* __restrict__ kp_u32)
{
    int idx = blockIdx.x * 256 + threadIdx.x;
    if (idx < 122880) {                        // qkvT[640][192]
        int col = idx / 192, k = idx % 192;
        qkvT[idx] = (col < 540 && k < 180) ? f2bf(qkv_w[k * 540 + col]) : (u16)0;
    } else if (idx < 172032) {                 // projT[256][192]
        int i = idx - 122880; int col = i / 192, k = i % 192;
        projT[i] = (col < 180 && k < 180) ? f2bf(proj_w[k * 180 + col]) : (u16)0;
    } else if (idx < 245760) {                 // fc1T[384][192]
        int i = idx - 172032; int col = i / 192, k = i % 192;
        fc1T[i] = (col < 360 && k < 180) ? f2bf(fc1_w[k * 360 + col]) : (u16)0;
    } else if (idx < 344064) {                 // fc2T[256][384]
        int i = idx - 245760; int col = i / 384, k = i % 384;
        fc2T[i] = (col < 180 && k < 360) ? f2bf(fc2_w[k * 180 + col]) : (u16)0;
    } else if (idx < 1228800) {                // bias5[(h*36+ch*4+mi)][lg][wv][l15][e] bf16
        int i = idx - 344064;
        int e = i & 15, l15 = (i >> 4) & 15, wv2 = (i >> 8) & 3, lg2 = (i >> 10) & 3;
        int cm36 = i >> 12;                    // 0..215
        int hh = cm36 / 36, cm = cm36 % 36;
        int ch = cm >> 2, mi = cm & 3;
        int ni = e >> 2, rr = e & 3;
        int q = wv2 * 64 + ni * 16 + l15;
        int key = ch * 64 + mi * 16 + lg2 * 4 + rr;
        bias5[i] = f2bf(rpb[rpi[q * 576 + key] * 6 + hh]);
    } else if (idx < 1628160) {                // K_pad border tokens (u32 x16)
        int i = idx - 1228800;
        int tok = i >> 4, wj = i & 15;
        int h = tok / 4160, b = tok % 4160, y, x;
        border_yx(b, y, x);
        kp_u32[((h * 264 + y) * 264 + x) * 16 + wj] = 0u;
    } else if (idx < 2021376) {                // K_pad interior dims 30,31
        int i = idx - 1628160;
        int h = i / 65536, t = i % 65536;
        int y = t >> 8, x = t & 255;
        kp_u32[((h * 264 + y + 4) * 264 + x + 4) * 16 + 15] = 0u;
    }
}

// ---------------------------------------------------------------------------
// LayerNorm: wave per row (180 f32 = 45 float4), writes bf16 [row][192]
// (cols 180..191 zeroed -> doubles as the attn-out pad fill, ao aliases xn)
// ---------------------------------------------------------------------------
__global__ __launch_bounds__(256)
void ln_k(const float* __restrict__ in, const float* __restrict__ w,
          const float* __restrict__ b, u16* __restrict__ out)
{
    int row = blockIdx.x * 4 + (threadIdx.x >> 6);
    int lane = threadIdx.x & 63;
    fvec4 v = {0.f, 0.f, 0.f, 0.f};
    if (lane < 45) v = *(const fvec4*)(in + (long)row * 180 + lane * 4);
    float s  = v.x + v.y + v.z + v.w;
    float sq = v.x * v.x + v.y * v.y + v.z * v.z + v.w * v.w;
    for (int m = 1; m < 64; m <<= 1) { s += __shfl_xor(s, m); sq += __shfl_xor(sq, m); }
    float mean = s * (1.f / 180.f);
    float var  = sq * (1.f / 180.f) - mean * mean;
    float rstd = rsqrtf(var + 1e-5f);
    if (lane < 45) {
        u16x4 o;
        #pragma unroll
        for (int j = 0; j < 4; j++) {
            int c = lane * 4 + j;
            o[j] = f2bf((v[j] - mean) * rstd * w[c] + b[c]);
        }
        *(u16x4*)(out + (long)row * 192 + lane * 4) = o;
    } else if (lane < 48) {
        u16x4 z = {0, 0, 0, 0};
        *(u16x4*)(out + (long)row * 192 + 180 + (lane - 45) * 4) = z;
    }
}

// ---------------------------------------------------------------------------
// V transpose -> window-blocked vT_w[h][w][32][576]; d30=1.0 (softmax denom),
// d31=0, OOB keys = 0. Block per (window, head).
// ---------------------------------------------------------------------------
__global__ __launch_bounds__(256)
void vtr_k(const u16* __restrict__ v_s, u16* __restrict__ vT_w)
{
    __shared__ u16 tile[32][616];
    const int w = ((blockIdx.x & 7) << 5) | (blockIdx.x >> 3);   // XCD swizzle
    const int h = blockIdx.y;
    const int wy = w >> 4, wx = w & 15;
    const int t = threadIdx.x;
    for (int n = t; n < 576; n += 256) {
        int oy = n / 24, ox = n - oy * 24;
        int y = wy * 16 - 4 + oy, x = wx * 16 - 4 + ox;
        bool ib = (y >= 0 && y < 256 && x >= 0 && x < 256);
        const u16* src = v_s + (((long)(y * 256 + x)) * 6 + h) * 32;
        #pragma unroll
        for (int dp = 0; dp < 4; dp++) {
            u16x8 v = {0,0,0,0,0,0,0,0};
            if (ib) v = *(const u16x8*)(src + dp * 8);
            #pragma unroll
            for (int j = 0; j < 8; j++) tile[dp * 8 + j][n] = v[j];
        }
        tile[30][n] = 0x3F80;   // 1.0
        tile[31][n] = 0;
    }
    __syncthreads();
    long base = ((long)(h * 256 + w)) * 32 * 576;
    #pragma unroll
    for (int i = 0; i < 9; i++) {
        int u = t + i * 256;            // u16x8 units; 72 per d-row
        int d = u / 72, g = u - d * 72;
        u16x8 vv = *(const u16x8*)(&tile[d][g * 8]);
        *(u16x8*)(vT_w + base + d * 576 + g * 8) = vv;
    }
}

// ---------------------------------------------------------------------------
// GEMM: C[M][N] = A[M][K]bf16 @ Bt[N][K]bf16, 128x128 tile, 4 waves 2x2.
// NO LDS, NO barriers: MFMA fragments loaded directly from global (16B/lane,
// 64B segments). K is tiny (6-12 steps) so per-step staging barriers cost
// more than they save; B panel is L2/L1-hot (blockIdx.x = N-panel so all
// row-blocks share it), A streamed once. Compiler free-pipelines steps.
// ---------------------------------------------------------------------------
template<int KTOT, int EPI>
__global__ __launch_bounds__(256)
void gemm_k(const u16* __restrict__ A, const u16* __restrict__ Bt,
            const float* __restrict__ bias, const float* __restrict__ resid,
            void* __restrict__ o0, void* __restrict__ o1, void* __restrict__ o2)
{
    constexpr int NK = KTOT / 32;
    const int tid = threadIdx.x;
    const int l = tid & 63, wv = tid >> 6;
    const int wm = wv >> 1, wn = wv & 1;
    const int l15 = l & 15, lg = l >> 4;
    const long rowb = (long)blockIdx.y * 128;
    const int  colb = blockIdx.x * 128;

    f32x4 acc[4][4];
    #pragma unroll
    for (int i = 0; i < 4; i++)
        #pragma unroll
        for (int j = 0; j < 4; j++) acc[i][j] = (f32x4){0.f, 0.f, 0.f, 0.f};

    const u16* Ab = A + (rowb + wm * 64 + l15) * KTOT + lg * 8;
    const u16* Bb = Bt + (long)(colb + wn * 64 + l15) * KTOT + lg * 8;

    for (int k = 0; k < NK; ++k) {
        bf16x8 af[4], bfr[4];
        #pragma unroll
        for (int mi = 0; mi < 4; mi++)
            af[mi] = *(const bf16x8*)(Ab + (mi * 16) * KTOT + k * 32);
        #pragma unroll
        for (int nd = 0; nd < 4; nd++)
            bfr[nd] = *(const bf16x8*)(Bb + (nd * 16) * KTOT + k * 32);
        #pragma unroll
        for (int mi = 0; mi < 4; mi++)
            #pragma unroll
            for (int nd = 0; nd < 4; nd++)
                acc[mi][nd] = __builtin_amdgcn_mfma_f32_16x16x32_bf16(af[mi], bfr[nd], acc[mi][nd], 0, 0, 0);
    }

    #pragma unroll
    for (int mi = 0; mi < 4; mi++) {
        #pragma unroll
        for (int nd = 0; nd < 4; nd++) {
            #pragma unroll
            for (int rr = 0; rr < 4; rr++) {
                long t = rowb + wm * 64 + mi * 16 + lg * 4 + rr;
                int c = colb + wn * 64 + nd * 16 + l15;
                float v = acc[mi][nd][rr];
                if (EPI == 0) {
                    if (c < 540) {
                        v += bias[c];
                        int y = (int)(t >> 8), x = (int)(t & 255);
                        if (c < 180) {
                            int hh = c / 30, d = c % 30;
                            int win = ((y >> 4) << 4) | (x >> 4);
                            int qrow = ((y & 15) << 4) | (x & 15);
                            ((u16*)o0)[(((long)(win * 6 + hh)) * 256 + qrow) * 32 + d] = f2bf(v * SCALE_Q);
                        } else if (c < 360) {
                            int c2 = c - 180; int hh = c2 / 30, d = c2 % 30;
                            ((u16*)o1)[(((long)hh * 264 + y + 4) * 264 + x + 4) * 32 + d] = f2bf(v);
                        } else {
                            int c2 = c - 360; int hh = c2 / 30, d = c2 % 30;
                            ((u16*)o2)[(t * 6 + hh) * 32 + d] = f2bf(v);
                        }
                    }
                } else if (EPI == 1) {
                    if (c < 180) ((float*)o0)[t * 180 + c] = v + bias[c] + resid[t * 180 + c];
                } else if (EPI == 2) {
                    float bb = (c < 360) ? bias[c] : 0.f;
                    float xx = v + bb;
                    float u2n = -2.f * xx * (0.7978845608f + 0.0356774081f * xx * xx);
                    float ge = xx / (1.f + __expf(u2n));
                    ((u16*)o0)[t * 384 + c] = f2bf(ge);
                } else {
                    if (c < 180) ((float*)o0)[t * 180 + c] = v + bias[c] + resid[t * 180 + c];
                }
            }
        }
    }
}

// ---------------------------------------------------------------------------
// Attention: block=(window,head), 4 waves x 64 q, 9 chunks of 64 keys.
// K staged via GLD16 from K_pad; V via 1 contiguous GLD16/wave from
// window-blocked vT_w. Swapped QK^T; P redistributed fully in-register
// (cvt_pk + permlane32_swap + permlane16_swap). Softmax denominator via
// vT_w d=30 == 1.0 (includes OOB keys, matching jnp.pad semantics).
// Bias: bf16 C-fragment-layout table, 8x16B loads/chunk, unpacked with one
// bit-op/element and fed as the QK^T MFMA C-INPUT (no separate adds).
// ---------------------------------------------------------------------------
__global__ __launch_bounds__(256)
void attn_k(const u16* __restrict__ q_g, const u16* __restrict__ K_pad,
            const u16* __restrict__ vT_w, const u16* __restrict__ bias5,
            u16* __restrict__ attn_out)
{
    __shared__ u16 kc[2][64 * 32];   // [key][dim32], dim-groups swizzled
    __shared__ u16 vt[2][32 * 64];   // [dim][key64], key-groups swizzled

    const int w = ((blockIdx.x & 7) << 5) | (blockIdx.x >> 3);   // XCD swizzle
    const int h = blockIdx.y;
    const int wy = w >> 4, wx = w & 15;
    const int tid = threadIdx.x;
    const int wv = tid >> 6, l = tid & 63;
    const int l15 = l & 15, lg = l >> 4;
    const int swzk = (l15 >> 1) & 3;
    const int swzv = l15 & 7;

    bf16x8 qb[4];
    #pragma unroll
    for (int ni = 0; ni < 4; ni++) {
        int qrow = wv * 64 + ni * 16 + l15;
        qb[ni] = *(const bf16x8*)(q_g + (((long)(w * 6 + h)) * 256 + qrow) * 32 + lg * 8);
    }

    f32x4 acc[2][4];
    #pragma unroll
    for (int i = 0; i < 2; i++)
        #pragma unroll
        for (int j = 0; j < 4; j++) acc[i][j] = (f32x4){0.f, 0.f, 0.f, 0.f};

    // K staging geometry: token tK = tid>>2, dim-group gtk (inverse-swizzled)
    const int tK = tid >> 2;
    const int gtk = (l & 3) ^ ((l >> 3) & 3);
    const int aK = (tK >= 48) ? 2 : (tK >= 24 ? 1 : 0);
    const int bK = tK - aK * 24;
    const u16* KbaseRow = K_pad + (((long)(h * 264 + wy * 16)) * 264 + wx * 16) * 32 + gtk * 8;
    // V staging: d = wv*8 + (l>>3), key-group gtv (inverse-swizzled)
    const int dV = tid >> 3;
    const int gtv = (l & 7) ^ (l >> 3);
    const u16* Vbase = vT_w + ((long)(h * 256 + w)) * 32 * 576 + dV * 576 + gtv * 8;
    // bf16 bias base for this lane (fragment layout)
    const u16* Bp = bias5 + (long)h * 147456 + ((lg * 4 + wv) * 16 + l15) * 16;

    // stage chunk 0
    GLD16(KbaseRow + ((long)aK * 264 + bK) * 32, (char*)kc[0] + wv * 1024);
    GLD16(Vbase, (char*)vt[0] + wv * 1024);

    #pragma unroll
    for (int ch = 0; ch < 9; ++ch) {
        __syncthreads();
        // bf16 bias for this chunk (issued before the stage loads)
        u16x8 bl[4], bh[4];
        #pragma unroll
        for (int mi = 0; mi < 4; mi++) {
            bl[mi] = *(const u16x8*)(Bp + (ch * 4 + mi) * 4096);
            bh[mi] = *(const u16x8*)(Bp + (ch * 4 + mi) * 4096 + 8);
        }
        if (ch < 8) {   // prefetch chunk ch+1
            int n = (ch + 1) * 64;
            int c1 = n / 24, c2 = n - c1 * 24;
            int bb2 = bK + c2;
            int t2 = bb2 >= 24;
            int oy = c1 + aK + t2, ox = bb2 - (t2 ? 24 : 0);
            GLD16(KbaseRow + ((long)oy * 264 + ox) * 32, (char*)kc[(ch + 1) & 1] + wv * 1024);
            GLD16(Vbase + (ch + 1) * 64, (char*)vt[(ch + 1) & 1] + wv * 1024);
        }
        const u16* kcur = kc[ch & 1];
        const u16* vcur = vt[ch & 1];

        #pragma unroll
        for (int ks = 0; ks < 2; ++ks) {
            int Wp[2][4][2];
            #pragma unroll
            for (int mih = 0; mih < 2; ++mih) {
                int mi = ks * 2 + mih;
                int key = ks * 32 + mih * 16 + l15;
                bf16x8 ka = *(const bf16x8*)(kcur + key * 32 + (lg ^ swzk) * 8);
                union { u16x8 v; unsigned d[4]; } ulo, uhi;
                ulo.v = bl[mi]; uhi.v = bh[mi];
                f32x4 s[4];
                #pragma unroll
                for (int ni = 0; ni < 4; ni++) {
                    unsigned dA = (ni < 2) ? ulo.d[(ni & 1) * 2]     : uhi.d[(ni & 1) * 2];
                    unsigned dB = (ni < 2) ? ulo.d[(ni & 1) * 2 + 1] : uhi.d[(ni & 1) * 2 + 1];
                    f32x4 ci;
                    ci[0] = __uint_as_float(dA << 16);
                    ci[1] = __uint_as_float(dA & 0xFFFF0000u);
                    ci[2] = __uint_as_float(dB << 16);
                    ci[3] = __uint_as_float(dB & 0xFFFF0000u);
                    s[ni] = ci;
                }
                __builtin_amdgcn_s_setprio(1);
                #pragma unroll
                for (int ni = 0; ni < 4; ni++)
                    s[ni] = __builtin_amdgcn_mfma_f32_16x16x32_bf16(ka, qb[ni], s[ni], 0, 0, 0);
                __builtin_amdgcn_s_setprio(0);
                #pragma unroll
                for (int ni = 0; ni < 4; ni++) {
                    float p0 = __expf(s[ni][0]);
                    float p1 = __expf(s[ni][1]);
                    float p2 = __expf(s[ni][2]);
                    float p3 = __expf(s[ni][3]);
                    int wlo, whi;
                    asm("v_cvt_pk_bf16_f32 %0, %1, %2" : "=v"(wlo) : "v"(p0), "v"(p1));
                    asm("v_cvt_pk_bf16_f32 %0, %1, %2" : "=v"(whi) : "v"(p2), "v"(p3));
                    Wp[mih][ni][0] = wlo;
                    Wp[mih][ni][1] = whi;
                }
            }
            bf16x8 va0 = *(const bf16x8*)(vcur + l15 * 64 + ((ks * 4 + lg) ^ swzv) * 8);
            bf16x8 va1 = *(const bf16x8*)(vcur + (16 + l15) * 64 + ((ks * 4 + lg) ^ swzv) * 8);
            #pragma unroll
            for (int ni = 0; ni < 4; ni++) {
                i32x2 r0 = __builtin_amdgcn_permlane32_swap(Wp[0][ni][0], Wp[1][ni][0], false, false);
                i32x2 r1 = __builtin_amdgcn_permlane32_swap(Wp[0][ni][1], Wp[1][ni][1], false, false);
                int wd0, wd1, wd2, wd3;
                xswap16(r0[0], r0[1], wd0, wd2);
                xswap16(r1[0], r1[1], wd1, wd3);
                union { int wd[4]; bf16x8 v; } pu;
                pu.wd[0] = wd0; pu.wd[1] = wd1; pu.wd[2] = wd2; pu.wd[3] = wd3;
                __builtin_amdgcn_s_setprio(1);
                acc[0][ni] = __builtin_amdgcn_mfma_f32_16x16x32_bf16(va0, pu.v, acc[0][ni], 0, 0, 0);
                acc[1][ni] = __builtin_amdgcn_mfma_f32_16x16x32_bf16(va1, pu.v, acc[1][ni], 0, 0, 0);
                __builtin_amdgcn_s_setprio(0);
            }
        }
    }

    // epilogue: O^T row d=30 holds sum(P); divide, scatter dims<30
    #pragma unroll
    for (int ni = 0; ni < 4; ni++) {
        float sum = __shfl(acc[1][ni][2], 48 + l15);   // d=30 at mi2=1,lg=3,rr=2
        float inv = 1.f / sum;
        int q = wv * 64 + ni * 16 + l15;
        int y = wy * 16 + (q >> 4), x = wx * 16 + (q & 15);
        long base = ((long)(y * 256 + x)) * 192 + h * 30;
        #pragma unroll
        for (int mi2 = 0; mi2 < 2; mi2++)
            #pragma unroll
            for (int rr = 0; rr < 4; rr++) {
                int dim = mi2 * 16 + lg * 4 + rr;
                if (dim < 30)
                    attn_out[base + dim] = f2bf(acc[mi2][ni][rr] * inv);
            }
    }
}

// ---------------------------------------------------------------------------
extern "C" void kernel_launch(void* const* d_in, const int* in_sizes, int n_in,
                              void* d_out, int out_size, void* d_ws, size_t ws_size,
                              hipStream_t stream)
{
    (void)in_sizes; (void)n_in; (void)out_size; (void)ws_size;
    const float* x      = (const float*)d_in[0];
    const int*   rpi    = (const int*)d_in[1];
    const float* n1w    = (const float*)d_in[2];
    const float* n1b    = (const float*)d_in[3];
    const float* qkv_w  = (const float*)d_in[4];
    const float* qkv_b  = (const float*)d_in[5];
    const float* rpb    = (const float*)d_in[6];
    const float* proj_w = (const float*)d_in[7];
    const float* proj_b = (const float*)d_in[8];
    const float* n2w    = (const float*)d_in[9];
    const float* n2b    = (const float*)d_in[10];
    const float* fc1_w  = (const float*)d_in[11];
    const float* fc1_b  = (const float*)d_in[12];
    const float* fc2_w  = (const float*)d_in[13];
    const float* fc2_b  = (const float*)d_in[14];
    float* out = (float*)d_out;

    char* ws = (char*)d_ws;
    size_t off = 0;
    auto alloc = [&](size_t bytes) -> void* {
        void* p = ws + off; off += (bytes + 511) & ~(size_t)511; return p;
    };
    u16*   xn     = (u16*)alloc(65536ull * 192 * 2);        // ln out; ao aliases
    u16*   q_g    = (u16*)alloc(65536ull * 192 * 2);        // [win][h][q][32]
    u16*   K_pad  = (u16*)alloc(6ull * 264 * 264 * 32 * 2); // [h][y][x][32]
    u16*   v_s    = (u16*)alloc(65536ull * 180 * 4);        // aliased with x2
    float* x2     = (float*)v_s;                            // v_s dead before proj
    u16*   vT_w   = (u16*)alloc(6ull * 256 * 32 * 576 * 2); // [h][w][d][key]
    u16*   bias5  = (u16*)alloc(6ull * 36 * 4 * 4 * 16 * 16 * 2);
    u16*   qkvT   = (u16*)alloc(640ull * 192 * 2);
    u16*   projT  = (u16*)alloc(256ull * 192 * 2);
    u16*   fc1T   = (u16*)alloc(384ull * 192 * 2);
    u16*   fc2T   = (u16*)alloc(256ull * 384 * 2);
    u16*   ao     = xn;    // ln_k zero-fills cols 180..191; attn fills 0..179
    u16*   h1     = q_g;   // fc1 out [t][384]: q_g+K_pad adjacent >= 50.3MB

    prep_k<<<dim3(7896), dim3(256), 0, stream>>>(qkv_w, proj_w, fc1_w, fc2_w,
        rpi, rpb, qkvT, projT, fc1T, fc2T, bias5, (unsigned*)K_pad);
    ln_k<<<dim3(16384), dim3(256), 0, stream>>>(x, n1w, n1b, xn);
    gemm_k<192, 0><<<dim3(5, 512), dim3(256), 0, stream>>>(
        xn, qkvT, qkv_b, (const float*)nullptr, q_g, K_pad, v_s);
    vtr_k<<<dim3(256, 6), dim3(256), 0, stream>>>(v_s, vT_w);
    attn_k<<<dim3(256, 6), dim3(256), 0, stream>>>(q_g, K_pad, vT_w, bias5, ao);
    gemm_k<192, 1><<<dim3(2, 512), dim3(256), 0, stream>>>(
        ao, projT, proj_b, x, x2, nullptr, nullptr);
    ln_k<<<dim3(16384), dim3(256), 0, stream>>>(x2, n2w, n2b, xn);
    gemm_k<192, 2><<<dim3(3, 512), dim3(256), 0, stream>>>(
        xn, fc1T, fc1_b, (const float*)nullptr, h1, nullptr, nullptr);
    gemm_k<384, 3><<<dim3(2, 512), dim3(256), 0, stream>>>(
        h1, fc2T, fc2_b, x2, out, nullptr, nullptr);
}

// Round 7
// 318.352 us; speedup vs baseline: 1.3174x; 1.3174x over previous
//
#include <hip/hip_runtime.h>

typedef float f32x4 __attribute__((ext_vector_type(4)));
typedef float fvec4 __attribute__((ext_vector_type(4)));
typedef __bf16 bf16x8 __attribute__((ext_vector_type(8)));
typedef unsigned short u16;
typedef u16 u16x8 __attribute__((ext_vector_type(8)));
typedef u16 u16x4 __attribute__((ext_vector_type(4)));
typedef int i32x2 __attribute__((ext_vector_type(2)));

#define SCALE_Q 0.18257418583505536f   /* 30^-0.5 */
#define LOG2E   1.4426950408889634f
#define SCALE_Q2 (SCALE_Q * LOG2E)     /* folded: exp(s) = 2^(s*log2e) */

__device__ __forceinline__ u16 f2bf(float f) {
    union { __bf16 h; u16 u; } cv; cv.h = (__bf16)f; return cv.u;
}
__device__ __forceinline__ float bf2f(u16 u) {
    union { __bf16 h; u16 u; } cv; cv.u = u; return (float)cv.h;
}
__device__ __forceinline__ float exp2_raw(float x) {
    float r;
    asm("v_exp_f32 %0, %1" : "=v"(r) : "v"(x));
    return r;
}

// async global->LDS, 16B per lane; LDS dest = wave-uniform base + lane*16
#define GLD16(gsrc, ldst) __builtin_amdgcn_global_load_lds( \
    (const __attribute__((address_space(1))) unsigned*)(gsrc), \
    (__attribute__((address_space(3))) unsigned*)(ldst), 16, 0, 0)

// lane^16 cross-exchange pair: u[l]=(l&16)?b[l^16]:a[l]; v[l]=(l&16)?b[l]:a[l^16]
__device__ __forceinline__ void xswap16(int a, int b, int& u, int& v) {
#if __has_builtin(__builtin_amdgcn_permlane16_swap)
    i32x2 r = __builtin_amdgcn_permlane16_swap(a, b, false, false);
    u = r[0]; v = r[1];
#else
    int sa = __builtin_amdgcn_ds_swizzle(a, 0x401F);
    int sb = __builtin_amdgcn_ds_swizzle(b, 0x401F);
    bool hi = (threadIdx.x & 16) != 0;
    u = hi ? sb : a;
    v = hi ? b : sa;
#endif
}

// ---------------------------------------------------------------------------
// prep: weight transposes (bf16 [col][k] padded), bias table (*log2e), K_pad
// ---------------------------------------------------------------------------
__device__ __forceinline__ void border_yx(int i, int& y, int& x) {
    if (i < 1056)      { y = i / 264; x = i % 264; }
    else if (i < 2112) { int j = i - 1056; y = 260 + j / 264; x = j % 264; }
    else               { int j = i - 2112; y = 4 + (j >> 3); int xx = j & 7;
                         x = (xx < 4) ? xx : 256 + xx; }
}

__global__ __launch_bounds__(256)
void prep_k(const float* __restrict__ qkv_w, const float* __restrict__ proj_w,
            const float* __restrict__ fc1_w, const float* __restrict__ fc2_w,
            const int* __restrict__ rpi, const float* __restrict__ rpb,
            u16* __restrict__ qkvT, u16* __restrict__ projT,
            u16* __restrict__ fc1T, u16* __restrict__ fc2T,
            u16* __restrict__ bias5, unsigned* __restrict__ kp_u32)
{
    int idx = blockIdx.x * 256 + threadIdx.x;
    if (idx < 122880) {                        // qkvT[640][192]
        int col = idx / 192, k = idx % 192;
        qkvT[idx] = (col < 540 && k < 180) ? f2bf(qkv_w[k * 540 + col]) : (u16)0;
    } else if (idx < 172032) {                 // projT[256][192]
        int i = idx - 122880; int col = i / 192, k = i % 192;
        projT[i] = (col < 180 && k < 180) ? f2bf(proj_w[k * 180 + col]) : (u16)0;
    } else if (idx < 245760) {                 // fc1T[384][192]
        int i = idx - 172032; int col = i / 192, k = i % 192;
        fc1T[i] = (col < 360 && k < 180) ? f2bf(fc1_w[k * 360 + col]) : (u16)0;
    } else if (idx < 344064) {                 // fc2T[256][384]
        int i = idx - 245760; int col = i / 384, k = i % 384;
        fc2T[i] = (col < 180 && k < 360) ? f2bf(fc2_w[k * 180 + col]) : (u16)0;
    } else if (idx < 1228800) {                // bias5[(h*36+ch*4+mi)][lg][wv][l15][e]
        int i = idx - 344064;
        int e = i & 15, l15 = (i >> 4) & 15, wv2 = (i >> 8) & 3, lg2 = (i >> 10) & 3;
        int cm36 = i >> 12;
        int hh = cm36 / 36, cm = cm36 % 36;
        int ch = cm >> 2, mi = cm & 3;
        int ni = e >> 2, rr = e & 3;
        int q = wv2 * 64 + ni * 16 + l15;
        int key = ch * 64 + mi * 16 + lg2 * 4 + rr;
        bias5[i] = f2bf(rpb[rpi[q * 576 + key] * 6 + hh] * LOG2E);
    } else if (idx < 1628160) {                // K_pad border tokens (u32 x16)
        int i = idx - 1228800;
        int tok = i >> 4, wj = i & 15;
        int h = tok / 4160, b = tok % 4160, y, x;
        border_yx(b, y, x);
        kp_u32[((h * 264 + y) * 264 + x) * 16 + wj] = 0u;
    } else if (idx < 2021376) {                // K_pad interior dims 30,31
        int i = idx - 1628160;
        int h = i / 65536, t = i % 65536;
        int y = t >> 8, x = t & 255;
        kp_u32[((h * 264 + y + 4) * 264 + x + 4) * 16 + 15] = 0u;
    }
}

// ---------------------------------------------------------------------------
// LayerNorm: wave per row (180 f32 = 45 float4), writes bf16 [row][192]
// ---------------------------------------------------------------------------
__global__ __launch_bounds__(256)
void ln_k(const float* __restrict__ in, const float* __restrict__ w,
          const float* __restrict__ b, u16* __restrict__ out)
{
    int row = blockIdx.x * 4 + (threadIdx.x >> 6);
    int lane = threadIdx.x & 63;
    fvec4 v = {0.f, 0.f, 0.f, 0.f};
    if (lane < 45) v = *(const fvec4*)(in + (long)row * 180 + lane * 4);
    float s  = v.x + v.y + v.z + v.w;
    float sq = v.x * v.x + v.y * v.y + v.z * v.z + v.w * v.w;
    for (int m = 1; m < 64; m <<= 1) { s += __shfl_xor(s, m); sq += __shfl_xor(sq, m); }
    float mean = s * (1.f / 180.f);
    float var  = sq * (1.f / 180.f) - mean * mean;
    float rstd = rsqrtf(var + 1e-5f);
    if (lane < 45) {
        u16x4 o;
        #pragma unroll
        for (int j = 0; j < 4; j++) {
            int c = lane * 4 + j;
            o[j] = f2bf((v[j] - mean) * rstd * w[c] + b[c]);
        }
        *(u16x4*)(out + (long)row * 192 + lane * 4) = o;
    } else if (lane < 48) {
        u16x4 z = {0, 0, 0, 0};
        *(u16x4*)(out + (long)row * 192 + 180 + (lane - 45) * 4) = z;
    }
}

// ---------------------------------------------------------------------------
// V transpose -> window-blocked vT_w[h][w][32][576]; d30=1.0 (softmax denom),
// d31=0, OOB keys = 0. Block per (window, head).
// ---------------------------------------------------------------------------
__global__ __launch_bounds__(256)
void vtr_k(const u16* __restrict__ v_s, u16* __restrict__ vT_w)
{
    __shared__ u16 tile[32][616];
    const int w = ((blockIdx.x & 7) << 5) | (blockIdx.x >> 3);   // XCD swizzle
    const int h = blockIdx.y;
    const int wy = w >> 4, wx = w & 15;
    const int t = threadIdx.x;
    for (int n = t; n < 576; n += 256) {
        int oy = n / 24, ox = n - oy * 24;
        int y = wy * 16 - 4 + oy, x = wx * 16 - 4 + ox;
        bool ib = (y >= 0 && y < 256 && x >= 0 && x < 256);
        const u16* src = v_s + (((long)(y * 256 + x)) * 6 + h) * 32;
        #pragma unroll
        for (int dp = 0; dp < 4; dp++) {
            u16x8 v = {0,0,0,0,0,0,0,0};
            if (ib) v = *(const u16x8*)(src + dp * 8);
            #pragma unroll
            for (int j = 0; j < 8; j++) tile[dp * 8 + j][n] = v[j];
        }
        tile[30][n] = 0x3F80;   // 1.0
        tile[31][n] = 0;
    }
    __syncthreads();
    long base = ((long)(h * 256 + w)) * 32 * 576;
    #pragma unroll
    for (int i = 0; i < 9; i++) {
        int u = t + i * 256;
        int d = u / 72, g = u - d * 72;
        u16x8 vv = *(const u16x8*)(&tile[d][g * 8]);
        *(u16x8*)(vT_w + base + d * 576 + g * 8) = vv;
    }
}

// ---------------------------------------------------------------------------
// GEMM (r2-proven structure): C[M][N] = A[M][K] @ Bt[N][K], 128x64 tile,
// 4 waves 2x2 (each 64x32), single LDS buffer, stage -> sync -> compute ->
// sync. 12KB LDS -> max occupancy; co-resident blocks hide the drain.
// ---------------------------------------------------------------------------
template<int KTOT, int EPI>
__global__ __launch_bounds__(256)
void gemm_k(const u16* __restrict__ A, const u16* __restrict__ Bt,
            const float* __restrict__ bias, const float* __restrict__ resid,
            void* __restrict__ o0, void* __restrict__ o1, void* __restrict__ o2)
{
    __shared__ u16 lds_a[128 * 32];
    __shared__ u16 lds_b[64 * 32];
    const int tid = threadIdx.x;
    const int l = tid & 63, wv = tid >> 6;
    const int wm = wv >> 1, wn = wv & 1;
    const int l15 = l & 15, lg = l >> 4;
    const int swz = (lg ^ ((l15 >> 1) & 3)) * 8;
    const long rowb = (long)blockIdx.x * 128;
    const int colb = blockIdx.y * 64;
    const f32x4 fz = {0.f, 0.f, 0.f, 0.f};

    f32x4 acc[4][2];
    #pragma unroll
    for (int i = 0; i < 4; i++) { acc[i][0] = fz; acc[i][1] = fz; }

    const int r = tid >> 2, g = tid & 3;
    const int gsw = (g ^ ((r >> 1) & 3)) * 8;
    char* dA0 = (char*)lds_a + wv * 1024;
    char* dA1 = (char*)lds_a + 4096 + wv * 1024;
    char* dB  = (char*)lds_b + wv * 1024;

    for (int kk = 0; kk < KTOT; kk += 32) {
        GLD16(A + (rowb + r) * KTOT + kk + gsw, dA0);
        GLD16(A + (rowb + 64 + r) * KTOT + kk + gsw, dA1);
        GLD16(Bt + (long)(colb + r) * KTOT + kk + gsw, dB);
        __syncthreads();
        bf16x8 af[4], bfr[2];
        #pragma unroll
        for (int mi = 0; mi < 4; mi++)
            af[mi] = *(const bf16x8*)(lds_a + (wm * 64 + mi * 16 + l15) * 32 + swz);
        #pragma unroll
        for (int nd = 0; nd < 2; nd++)
            bfr[nd] = *(const bf16x8*)(lds_b + (wn * 32 + nd * 16 + l15) * 32 + swz);
        #pragma unroll
        for (int mi = 0; mi < 4; mi++)
            #pragma unroll
            for (int nd = 0; nd < 2; nd++)
                acc[mi][nd] = __builtin_amdgcn_mfma_f32_16x16x32_bf16(af[mi], bfr[nd], acc[mi][nd], 0, 0, 0);
        __syncthreads();
    }

    #pragma unroll
    for (int mi = 0; mi < 4; mi++) {
        #pragma unroll
        for (int nd = 0; nd < 2; nd++) {
            #pragma unroll
            for (int rr = 0; rr < 4; rr++) {
                long t = rowb + wm * 64 + mi * 16 + lg * 4 + rr;
                int c = colb + wn * 32 + nd * 16 + l15;
                float v = acc[mi][nd][rr];
                if (EPI == 0) {
                    if (c < 540) {
                        v += bias[c];
                        int y = (int)(t >> 8), x = (int)(t & 255);
                        if (c < 180) {
                            int hh = c / 30, d = c % 30;
                            int win = ((y >> 4) << 4) | (x >> 4);
                            int qrow = ((y & 15) << 4) | (x & 15);
                            ((u16*)o0)[(((long)(win * 6 + hh)) * 256 + qrow) * 32 + d] = f2bf(v * SCALE_Q2);
                        } else if (c < 360) {
                            int c2 = c - 180; int hh = c2 / 30, d = c2 % 30;
                            ((u16*)o1)[(((long)hh * 264 + y + 4) * 264 + x + 4) * 32 + d] = f2bf(v);
                        } else {
                            int c2 = c - 360; int hh = c2 / 30, d = c2 % 30;
                            ((u16*)o2)[(t * 6 + hh) * 32 + d] = f2bf(v);
                        }
                    }
                } else if (EPI == 1) {
                    if (c < 180) ((float*)o0)[t * 180 + c] = v + bias[c] + resid[t * 180 + c];
                } else if (EPI == 2) {
                    float bb = (c < 360) ? bias[c] : 0.f;
                    float xx = v + bb;
                    float u2n = -2.f * xx * (0.7978845608f + 0.0356774081f * xx * xx);
                    float ge = xx / (1.f + __expf(u2n));
                    ((u16*)o0)[t * 384 + c] = f2bf(ge);
                } else {
                    if (c < 180) ((float*)o0)[t * 180 + c] = v + bias[c] + resid[t * 180 + c];
                }
            }
        }
    }
}

// ---------------------------------------------------------------------------
// Attention: block=(window,head), 4 waves x 64 q, 9 chunks of 64 keys.
// K staged via GLD16 from K_pad; V via 1 contiguous GLD16/wave from vT_w.
// Swapped QK^T; P redistributed in-register (cvt_pk + permlane swaps).
// Softmax denom via vT_w d=30 == 1.0. Bias (pre-scaled by log2e) fed as the
// QK^T MFMA C-INPUT; Q pre-scaled by SCALE*log2e -> P = v_exp_f32(S) direct
// (no v_mul per exp). No setprio (4-wave lockstep = m190 null regime).
// ---------------------------------------------------------------------------
__global__ __launch_bounds__(256)
void attn_k(const u16* __restrict__ q_g, const u16* __restrict__ K_pad,
            const u16* __restrict__ vT_w, const u16* __restrict__ bias5,
            u16* __restrict__ attn_out)
{
    __shared__ u16 kc[2][64 * 32];
    __shared__ u16 vt[2][32 * 64];

    const int w = ((blockIdx.x & 7) << 5) | (blockIdx.x >> 3);   // XCD swizzle
    const int h = blockIdx.y;
    const int wy = w >> 4, wx = w & 15;
    const int tid = threadIdx.x;
    const int wv = tid >> 6, l = tid & 63;
    const int l15 = l & 15, lg = l >> 4;
    const int swzk = (l15 >> 1) & 3;
    const int swzv = l15 & 7;

    bf16x8 qb[4];
    #pragma unroll
    for (int ni = 0; ni < 4; ni++) {
        int qrow = wv * 64 + ni * 16 + l15;
        qb[ni] = *(const bf16x8*)(q_g + (((long)(w * 6 + h)) * 256 + qrow) * 32 + lg * 8);
    }

    f32x4 acc[2][4];
    #pragma unroll
    for (int i = 0; i < 2; i++)
        #pragma unroll
        for (int j = 0; j < 4; j++) acc[i][j] = (f32x4){0.f, 0.f, 0.f, 0.f};

    const int tK = tid >> 2;
    const int gtk = (l & 3) ^ ((l >> 3) & 3);
    const int aK = (tK >= 48) ? 2 : (tK >= 24 ? 1 : 0);
    const int bK = tK - aK * 24;
    const u16* KbaseRow = K_pad + (((long)(h * 264 + wy * 16)) * 264 + wx * 16) * 32 + gtk * 8;
    const int dV = tid >> 3;
    const int gtv = (l & 7) ^ (l >> 3);
    const u16* Vbase = vT_w + ((long)(h * 256 + w)) * 32 * 576 + dV * 576 + gtv * 8;
    const u16* Bp = bias5 + (long)h * 147456 + ((lg * 4 + wv) * 16 + l15) * 16;

    GLD16(KbaseRow + ((long)aK * 264 + bK) * 32, (char*)kc[0] + wv * 1024);
    GLD16(Vbase, (char*)vt[0] + wv * 1024);

    #pragma unroll
    for (int ch = 0; ch < 9; ++ch) {
        __syncthreads();
        u16x8 bl[4], bh[4];
        #pragma unroll
        for (int mi = 0; mi < 4; mi++) {
            bl[mi] = *(const u16x8*)(Bp + (ch * 4 + mi) * 4096);
            bh[mi] = *(const u16x8*)(Bp + (ch * 4 + mi) * 4096 + 8);
        }
        if (ch < 8) {
            int n = (ch + 1) * 64;
            int c1 = n / 24, c2 = n - c1 * 24;
            int bb2 = bK + c2;
            int t2 = bb2 >= 24;
            int oy = c1 + aK + t2, ox = bb2 - (t2 ? 24 : 0);
            GLD16(KbaseRow + ((long)oy * 264 + ox) * 32, (char*)kc[(ch + 1) & 1] + wv * 1024);
            GLD16(Vbase + (ch + 1) * 64, (char*)vt[(ch + 1) & 1] + wv * 1024);
        }
        const u16* kcur = kc[ch & 1];
        const u16* vcur = vt[ch & 1];

        #pragma unroll
        for (int ks = 0; ks < 2; ++ks) {
            int Wp[2][4][2];
            #pragma unroll
            for (int mih = 0; mih < 2; ++mih) {
                int mi = ks * 2 + mih;
                int key = ks * 32 + mih * 16 + l15;
                bf16x8 ka = *(const bf16x8*)(kcur + key * 32 + (lg ^ swzk) * 8);
                union { u16x8 v; unsigned d[4]; } ulo, uhi;
                ulo.v = bl[mi]; uhi.v = bh[mi];
                f32x4 s[4];
                #pragma unroll
                for (int ni = 0; ni < 4; ni++) {
                    unsigned dA = (ni < 2) ? ulo.d[(ni & 1) * 2]     : uhi.d[(ni & 1) * 2];
                    unsigned dB = (ni < 2) ? ulo.d[(ni & 1) * 2 + 1] : uhi.d[(ni & 1) * 2 + 1];
                    f32x4 ci;
                    ci[0] = __uint_as_float(dA << 16);
                    ci[1] = __uint_as_float(dA & 0xFFFF0000u);
                    ci[2] = __uint_as_float(dB << 16);
                    ci[3] = __uint_as_float(dB & 0xFFFF0000u);
                    s[ni] = ci;
                }
                #pragma unroll
                for (int ni = 0; ni < 4; ni++)
                    s[ni] = __builtin_amdgcn_mfma_f32_16x16x32_bf16(ka, qb[ni], s[ni], 0, 0, 0);
                #pragma unroll
                for (int ni = 0; ni < 4; ni++) {
                    float p0 = exp2_raw(s[ni][0]);
                    float p1 = exp2_raw(s[ni][1]);
                    float p2 = exp2_raw(s[ni][2]);
                    float p3 = exp2_raw(s[ni][3]);
                    int wlo, whi;
                    asm("v_cvt_pk_bf16_f32 %0, %1, %2" : "=v"(wlo) : "v"(p0), "v"(p1));
                    asm("v_cvt_pk_bf16_f32 %0, %1, %2" : "=v"(whi) : "v"(p2), "v"(p3));
                    Wp[mih][ni][0] = wlo;
                    Wp[mih][ni][1] = whi;
                }
            }
            bf16x8 va0 = *(const bf16x8*)(vcur + l15 * 64 + ((ks * 4 + lg) ^ swzv) * 8);
            bf16x8 va1 = *(const bf16x8*)(vcur + (16 + l15) * 64 + ((ks * 4 + lg) ^ swzv) * 8);
            #pragma unroll
            for (int ni = 0; ni < 4; ni++) {
                i32x2 r0 = __builtin_amdgcn_permlane32_swap(Wp[0][ni][0], Wp[1][ni][0], false, false);
                i32x2 r1 = __builtin_amdgcn_permlane32_swap(Wp[0][ni][1], Wp[1][ni][1], false, false);
                int wd0, wd1, wd2, wd3;
                xswap16(r0[0], r0[1], wd0, wd2);
                xswap16(r1[0], r1[1], wd1, wd3);
                union { int wd[4]; bf16x8 v; } pu;
                pu.wd[0] = wd0; pu.wd[1] = wd1; pu.wd[2] = wd2; pu.wd[3] = wd3;
                acc[0][ni] = __builtin_amdgcn_mfma_f32_16x16x32_bf16(va0, pu.v, acc[0][ni], 0, 0, 0);
                acc[1][ni] = __builtin_amdgcn_mfma_f32_16x16x32_bf16(va1, pu.v, acc[1][ni], 0, 0, 0);
            }
        }
    }

    // epilogue: O^T row d=30 holds sum(P); divide, scatter dims<30
    #pragma unroll
    for (int ni = 0; ni < 4; ni++) {
        float sum = __shfl(acc[1][ni][2], 48 + l15);
        float inv = 1.f / sum;
        int q = wv * 64 + ni * 16 + l15;
        int y = wy * 16 + (q >> 4), x = wx * 16 + (q & 15);
        long base = ((long)(y * 256 + x)) * 192 + h * 30;
        #pragma unroll
        for (int mi2 = 0; mi2 < 2; mi2++)
            #pragma unroll
            for (int rr = 0; rr < 4; rr++) {
                int dim = mi2 * 16 + lg * 4 + rr;
                if (dim < 30)
                    attn_out[base + dim] = f2bf(acc[mi2][ni][rr] * inv);
            }
    }
}

// ---------------------------------------------------------------------------
extern "C" void kernel_launch(void* const* d_in, const int* in_sizes, int n_in,
                              void* d_out, int out_size, void* d_ws, size_t ws_size,
                              hipStream_t stream)
{
    (void)in_sizes; (void)n_in; (void)out_size; (void)ws_size;
    const float* x      = (const float*)d_in[0];
    const int*   rpi    = (const int*)d_in[1];
    const float* n1w    = (const float*)d_in[2];
    const float* n1b    = (const float*)d_in[3];
    const float* qkv_w  = (const float*)d_in[4];
    const float* qkv_b  = (const float*)d_in[5];
    const float* rpb    = (const float*)d_in[6];
    const float* proj_w = (const float*)d_in[7];
    const float* proj_b = (const float*)d_in[8];
    const float* n2w    = (const float*)d_in[9];
    const float* n2b    = (const float*)d_in[10];
    const float* fc1_w  = (const float*)d_in[11];
    const float* fc1_b  = (const float*)d_in[12];
    const float* fc2_w  = (const float*)d_in[13];
    const float* fc2_b  = (const float*)d_in[14];
    float* out = (float*)d_out;

    char* ws = (char*)d_ws;
    size_t off = 0;
    auto alloc = [&](size_t bytes) -> void* {
        void* p = ws + off; off += (bytes + 511) & ~(size_t)511; return p;
    };
    u16*   xn     = (u16*)alloc(65536ull * 192 * 2);        // ln out; ao aliases
    u16*   q_g    = (u16*)alloc(65536ull * 192 * 2);        // [win][h][q][32]
    u16*   K_pad  = (u16*)alloc(6ull * 264 * 264 * 32 * 2); // [h][y][x][32]
    u16*   v_s    = (u16*)alloc(65536ull * 180 * 4);        // aliased with x2
    float* x2     = (float*)v_s;                            // v_s dead before proj
    u16*   vT_w   = (u16*)alloc(6ull * 256 * 32 * 576 * 2); // [h][w][d][key]
    u16*   bias5  = (u16*)alloc(6ull * 36 * 4 * 4 * 16 * 16 * 2);
    u16*   qkvT   = (u16*)alloc(640ull * 192 * 2);
    u16*   projT  = (u16*)alloc(256ull * 192 * 2);
    u16*   fc1T   = (u16*)alloc(384ull * 192 * 2);
    u16*   fc2T   = (u16*)alloc(256ull * 384 * 2);
    u16*   ao     = xn;    // ln_k zero-fills cols 180..191; attn fills 0..179
    u16*   h1     = q_g;   // fc1 out [t][384]: q_g+K_pad adjacent >= 50.3MB

    prep_k<<<dim3(7896), dim3(256), 0, stream>>>(qkv_w, proj_w, fc1_w, fc2_w,
        rpi, rpb, qkvT, projT, fc1T, fc2T, bias5, (unsigned*)K_pad);
    ln_k<<<dim3(16384), dim3(256), 0, stream>>>(x, n1w, n1b, xn);
    gemm_k<192, 0><<<dim3(512, 9), dim3(256), 0, stream>>>(
        xn, qkvT, qkv_b, (const float*)nullptr, q_g, K_pad, v_s);
    vtr_k<<<dim3(256, 6), dim3(256), 0, stream>>>(v_s, vT_w);
    attn_k<<<dim3(256, 6), dim3(256), 0, stream>>>(q_g, K_pad, vT_w, bias5, ao);
    gemm_k<192, 1><<<dim3(512, 3), dim3(256), 0, stream>>>(
        ao, projT, proj_b, x, x2, nullptr, nullptr);
    ln_k<<<dim3(16384), dim3(256), 0, stream>>>(x2, n2w, n2b, xn);
    gemm_k<192, 2><<<dim3(512, 6), dim3(256), 0, stream>>>(
        xn, fc1T, fc1_b, (const float*)nullptr, h1, nullptr, nullptr);
    gemm_k<384, 3><<<dim3(512, 3), dim3(256), 0, stream>>>(
        h1, fc2T, fc2_b, x2, out, nullptr, nullptr);
}